// Round 1
// baseline (52.098 us; speedup 1.0000x reference)
//
#include <hip/hip_runtime.h>

#define TPB 256
#define IPT 8          // source points per thread
#define NIB 2          // i-blocks: N / (TPB*IPT) = 4096/2048
#define NPTS 4096
#define NB 8

// Partial chamfer mins: grid = 2(dir) * 8(batch) * NIB * njb blocks.
// Each block: stage tgt j-chunk into LDS as (x,y,z,||g||^2), each thread keeps
// IPT source points in registers, computes min_j(gg - 2 p.g) over the chunk,
// writes mn + ||p||^2 to partial[(dir*NB+b)*njb + jb][i].
__global__ __launch_bounds__(TPB) void cd_partial_kernel(
    const float* __restrict__ pred, const float* __restrict__ gt,
    float* __restrict__ partial, int njb, int jchunk) {
  extern __shared__ float4 sg[];

  int bid = blockIdx.x;
  int jb  = bid % njb;  bid /= njb;
  int ib  = bid & (NIB - 1); bid /= NIB;
  int b   = bid & (NB - 1);  bid /= NB;
  int dir = bid;  // 0: src=pred,tgt=gt (min over j) ; 1: src=gt,tgt=pred (min over i)

  const float* src = (dir == 0) ? pred : gt;
  const float* tgt = (dir == 0) ? gt : pred;
  src += (size_t)b * NPTS * 3;
  tgt += (size_t)b * NPTS * 3;

  const int t = threadIdx.x;

  // stage target chunk into LDS
  for (int p = t; p < jchunk; p += TPB) {
    int j = jb * jchunk + p;
    float gx = tgt[j * 3 + 0];
    float gy = tgt[j * 3 + 1];
    float gz = tgt[j * 3 + 2];
    sg[p] = make_float4(gx, gy, gz, fmaf(gx, gx, fmaf(gy, gy, gz * gz)));
  }

  // load my IPT source points
  float qx[IPT], qy[IPT], qz[IPT], pp[IPT], mn[IPT];
  const int ibase = ib * (TPB * IPT);
#pragma unroll
  for (int k = 0; k < IPT; ++k) {
    int i = ibase + k * TPB + t;
    float x = src[i * 3 + 0];
    float y = src[i * 3 + 1];
    float z = src[i * 3 + 2];
    qx[k] = -2.0f * x;
    qy[k] = -2.0f * y;
    qz[k] = -2.0f * z;
    pp[k] = fmaf(x, x, fmaf(y, y, z * z));
    mn[k] = 3.4e38f;
  }
  __syncthreads();

  // main loop: 1 broadcast ds_read_b128 + IPT*(3 FMA + 1 min) per j
#pragma unroll 4
  for (int p = 0; p < jchunk; ++p) {
    float4 g = sg[p];
#pragma unroll
    for (int k = 0; k < IPT; ++k) {
      float v = fmaf(qx[k], g.x, fmaf(qy[k], g.y, fmaf(qz[k], g.z, g.w)));
      mn[k] = fminf(mn[k], v);
    }
  }

  float* outp = partial + ((size_t)((dir * NB + b) * njb + jb)) * NPTS;
#pragma unroll
  for (int k = 0; k < IPT; ++k) {
    outp[ibase + k * TPB + t] = mn[k] + pp[k];
  }
}

// Reduce: for each (dir,b,i) slice take min over njb partials, sum everything,
// scale by 1/NB, atomicAdd into out (out pre-zeroed via memset).
__global__ __launch_bounds__(TPB) void cd_reduce_kernel(
    const float* __restrict__ partial, float* __restrict__ out, int njb) {
  const int total = 2 * NB * NPTS;
  int tid = blockIdx.x * TPB + threadIdx.x;
  float local = 0.0f;
  for (int s = tid; s < total; s += gridDim.x * TPB) {
    int db = s >> 12;          // (dir*NB + b), since NPTS = 4096
    int i  = s & (NPTS - 1);
    const float* p = partial + (size_t)db * njb * NPTS + i;
    float m = p[0];
    for (int jb = 1; jb < njb; ++jb) m = fminf(m, p[(size_t)jb * NPTS]);
    local += m;
  }
  // wave reduce
#pragma unroll
  for (int off = 32; off > 0; off >>= 1) local += __shfl_down(local, off, 64);
  __shared__ float red[TPB / 64];
  int wave = threadIdx.x >> 6;
  int lane = threadIdx.x & 63;
  if (lane == 0) red[wave] = local;
  __syncthreads();
  if (threadIdx.x == 0) {
    float s = 0.0f;
    for (int w = 0; w < TPB / 64; ++w) s += red[w];
    atomicAdd(out, s * (1.0f / NB));
  }
}

extern "C" void kernel_launch(void* const* d_in, const int* in_sizes, int n_in,
                              void* d_out, int out_size, void* d_ws, size_t ws_size,
                              hipStream_t stream) {
  const float* pred = (const float*)d_in[0];
  const float* gt   = (const float*)d_in[1];
  float* out        = (float*)d_out;
  float* partial    = (float*)d_ws;

  // choose j-split count to fit workspace: need 2*NB*njb*NPTS floats
  int njb = 8;
  {
    size_t per_jb = (size_t)2 * NB * NPTS * sizeof(float);  // 256 KB per jb level
    size_t need = per_jb * njb;
    if (ws_size < need) {
      njb = (int)(ws_size / per_jb);
      if (njb < 1) njb = 1;
      while (njb & (njb - 1)) njb &= njb - 1;  // power of two so it divides 4096
      if (njb > 8) njb = 8;
    }
  }
  int jchunk = NPTS / njb;

  hipMemsetAsync(d_out, 0, sizeof(float), stream);

  dim3 grid(2 * NB * NIB * njb);
  size_t lds = (size_t)jchunk * sizeof(float4);
  cd_partial_kernel<<<grid, TPB, lds, stream>>>(pred, gt, partial, njb, jchunk);
  cd_reduce_kernel<<<64, TPB, 0, stream>>>(partial, out, njb);
}

// Round 2
// 43.024 us; speedup vs baseline: 1.2109x; 1.2109x over previous
//
#include <hip/hip_runtime.h>

#define TPB 256
#define IPT 8          // source points per thread
#define NIB 2          // i-blocks: N / (TPB*IPT) = 4096/2048
#define NPTS 4096
#define NB 8

// Partial chamfer mins: grid = 2(dir) * 8(batch) * NIB * njb blocks.
// Each block: stage tgt j-chunk into LDS as (x,y,z,||g||^2), each thread keeps
// IPT source points in registers, computes min_j(gg - 2 p.g) over the chunk,
// writes mn + ||p||^2 to partial[(dir*NB+b)*njb + jb][i].
// njb=32 -> 1024 blocks = 4 blocks/CU = 16 waves/CU for latency hiding.
__global__ __launch_bounds__(TPB, 4) void cd_partial_kernel(
    const float* __restrict__ pred, const float* __restrict__ gt,
    float* __restrict__ partial, int njb, int jchunk) {
  extern __shared__ float4 sg[];

  int bid = blockIdx.x;
  int jb  = bid % njb;  bid /= njb;
  int ib  = bid & (NIB - 1); bid /= NIB;
  int b   = bid & (NB - 1);  bid /= NB;
  int dir = bid;  // 0: src=pred,tgt=gt ; 1: src=gt,tgt=pred

  const float* src = (dir == 0) ? pred : gt;
  const float* tgt = (dir == 0) ? gt : pred;
  src += (size_t)b * NPTS * 3;
  tgt += (size_t)b * NPTS * 3;

  const int t = threadIdx.x;

  // stage target chunk into LDS
  for (int p = t; p < jchunk; p += TPB) {
    int j = jb * jchunk + p;
    float gx = tgt[j * 3 + 0];
    float gy = tgt[j * 3 + 1];
    float gz = tgt[j * 3 + 2];
    sg[p] = make_float4(gx, gy, gz, fmaf(gx, gx, fmaf(gy, gy, gz * gz)));
  }

  // load my IPT source points
  float qx[IPT], qy[IPT], qz[IPT], pp[IPT], mn[IPT];
  const int ibase = ib * (TPB * IPT);
#pragma unroll
  for (int k = 0; k < IPT; ++k) {
    int i = ibase + k * TPB + t;
    float x = src[i * 3 + 0];
    float y = src[i * 3 + 1];
    float z = src[i * 3 + 2];
    qx[k] = -2.0f * x;
    qy[k] = -2.0f * y;
    qz[k] = -2.0f * z;
    pp[k] = fmaf(x, x, fmaf(y, y, z * z));
    mn[k] = 3.4e38f;
  }
  __syncthreads();

  // main loop: process j in pairs so fminf(mn, fminf(v0,v1)) folds to v_min3.
  // Per 2 j's per k: 6 FMA + 1 min3 = 7 VALU (vs 8 unpaired).
#pragma unroll 4
  for (int p = 0; p < jchunk; p += 2) {
    float4 g0 = sg[p];
    float4 g1 = sg[p + 1];
#pragma unroll
    for (int k = 0; k < IPT; ++k) {
      float v0 = fmaf(qx[k], g0.x, fmaf(qy[k], g0.y, fmaf(qz[k], g0.z, g0.w)));
      float v1 = fmaf(qx[k], g1.x, fmaf(qy[k], g1.y, fmaf(qz[k], g1.z, g1.w)));
      mn[k] = fminf(mn[k], fminf(v0, v1));
    }
  }

  float* outp = partial + ((size_t)((dir * NB + b) * njb + jb)) * NPTS;
#pragma unroll
  for (int k = 0; k < IPT; ++k) {
    outp[ibase + k * TPB + t] = mn[k] + pp[k];
  }
}

// Reduce: for each (dir,b,i) slice take min over njb partials, sum everything,
// scale by 1/NB, atomicAdd into out (out pre-zeroed via memset).
__global__ __launch_bounds__(TPB) void cd_reduce_kernel(
    const float* __restrict__ partial, float* __restrict__ out, int njb) {
  const int total = 2 * NB * NPTS;
  int tid = blockIdx.x * TPB + threadIdx.x;
  float local = 0.0f;
  for (int s = tid; s < total; s += gridDim.x * TPB) {
    int db = s >> 12;          // (dir*NB + b), since NPTS = 4096
    int i  = s & (NPTS - 1);
    const float* p = partial + (size_t)db * njb * NPTS + i;
    float m = p[0];
    for (int jb = 1; jb < njb; ++jb) m = fminf(m, p[(size_t)jb * NPTS]);
    local += m;
  }
  // wave reduce
#pragma unroll
  for (int off = 32; off > 0; off >>= 1) local += __shfl_down(local, off, 64);
  __shared__ float red[TPB / 64];
  int wave = threadIdx.x >> 6;
  int lane = threadIdx.x & 63;
  if (lane == 0) red[wave] = local;
  __syncthreads();
  if (threadIdx.x == 0) {
    float s = 0.0f;
    for (int w = 0; w < TPB / 64; ++w) s += red[w];
    atomicAdd(out, s * (1.0f / NB));
  }
}

extern "C" void kernel_launch(void* const* d_in, const int* in_sizes, int n_in,
                              void* d_out, int out_size, void* d_ws, size_t ws_size,
                              hipStream_t stream) {
  const float* pred = (const float*)d_in[0];
  const float* gt   = (const float*)d_in[1];
  float* out        = (float*)d_out;
  float* partial    = (float*)d_ws;

  // choose j-split count to fit workspace: need 2*NB*njb*NPTS floats
  int njb = 32;
  {
    size_t per_jb = (size_t)2 * NB * NPTS * sizeof(float);  // 256 KB per jb level
    size_t need = per_jb * njb;
    if (ws_size < need) {
      njb = (int)(ws_size / per_jb);
      if (njb < 1) njb = 1;
      while (njb & (njb - 1)) njb &= njb - 1;  // power of two so it divides 4096
      if (njb > 32) njb = 32;
    }
  }
  int jchunk = NPTS / njb;

  hipMemsetAsync(d_out, 0, sizeof(float), stream);

  dim3 grid(2 * NB * NIB * njb);
  size_t lds = (size_t)jchunk * sizeof(float4);
  cd_partial_kernel<<<grid, TPB, lds, stream>>>(pred, gt, partial, njb, jchunk);
  cd_reduce_kernel<<<256, TPB, 0, stream>>>(partial, out, njb);
}